// Round 1
// baseline (1818.828 us; speedup 1.0000x reference)
//
#include <hip/hip_runtime.h>
#include <math.h>

#define NB 2
#define NN 50000
#define NE 800000
#define FIN 1433
#define HD 64   // H1*C1
#define C2c 7

static __device__ __forceinline__ float leaky(float e) { return e > 0.f ? e : 0.2f * e; }

// ---------------- GEMM1: h1 = x @ W1  (N x 1433) @ (1433 x 64) ----------------
__global__ __launch_bounds__(256) void gemm1_kernel(const float* __restrict__ x,
                                                    const float* __restrict__ W,
                                                    float* __restrict__ h1) {
    const int b = blockIdx.y;
    const int row0 = blockIdx.x * 64;
    const float* xb = x + (size_t)b * NN * FIN;
    float* hb = h1 + (size_t)b * NN * HD;

    __shared__ float As[16 * 65];  // [k][row], stride 65 kills write conflicts
    __shared__ float Bs[16 * 64];  // [k][col]

    const int tid = threadIdx.x;
    const int tx = tid & 15;   // col group (4 cols)
    const int ty = tid >> 4;   // row group (4 rows)

    float acc[4][4];
#pragma unroll
    for (int i = 0; i < 4; i++)
#pragma unroll
        for (int j = 0; j < 4; j++) acc[i][j] = 0.f;

    for (int kt = 0; kt < FIN; kt += 16) {
#pragma unroll
        for (int i = 0; i < 4; i++) {  // A tile: 64 rows x 16 k
            int idx = tid + i * 256;
            int r = idx >> 4, kk = idx & 15;
            int gr = row0 + r, gk = kt + kk;
            float v = 0.f;
            if (gr < NN && gk < FIN) v = xb[(size_t)gr * FIN + gk];
            As[kk * 65 + r] = v;
        }
#pragma unroll
        for (int i = 0; i < 4; i++) {  // B tile: 16 k x 64 col
            int idx = tid + i * 256;
            int kk = idx >> 6, c = idx & 63;
            int gk = kt + kk;
            float v = 0.f;
            if (gk < FIN) v = W[gk * 64 + c];
            Bs[kk * 64 + c] = v;
        }
        __syncthreads();
#pragma unroll
        for (int kk = 0; kk < 16; kk++) {
            float a0 = As[kk * 65 + ty * 4 + 0];
            float a1 = As[kk * 65 + ty * 4 + 1];
            float a2 = As[kk * 65 + ty * 4 + 2];
            float a3 = As[kk * 65 + ty * 4 + 3];
            const float4 bv = *(const float4*)&Bs[kk * 64 + tx * 4];
            acc[0][0] += a0 * bv.x; acc[0][1] += a0 * bv.y; acc[0][2] += a0 * bv.z; acc[0][3] += a0 * bv.w;
            acc[1][0] += a1 * bv.x; acc[1][1] += a1 * bv.y; acc[1][2] += a1 * bv.z; acc[1][3] += a1 * bv.w;
            acc[2][0] += a2 * bv.x; acc[2][1] += a2 * bv.y; acc[2][2] += a2 * bv.z; acc[2][3] += a2 * bv.w;
            acc[3][0] += a3 * bv.x; acc[3][1] += a3 * bv.y; acc[3][2] += a3 * bv.z; acc[3][3] += a3 * bv.w;
        }
        __syncthreads();
    }
#pragma unroll
    for (int i = 0; i < 4; i++) {
        int row = row0 + ty * 4 + i;
        if (row < NN) {
            float4 v = make_float4(acc[i][0], acc[i][1], acc[i][2], acc[i][3]);
            *(float4*)&hb[(size_t)row * 64 + tx * 4] = v;
        }
    }
}

// ---------------- per-node attention coefficients, layer 1 ----------------
__global__ void coef1_kernel(const float* __restrict__ h1, const float* __restrict__ a_src,
                             const float* __restrict__ a_dst, float* __restrict__ es,
                             float* __restrict__ ed) {
    int i = blockIdx.x * blockDim.x + threadIdx.x;  // over B*N*8
    if (i >= NB * NN * 8) return;
    int h = i & 7;
    int n = i >> 3;
    const float* hp = h1 + (size_t)n * 64 + h * 8;
    float s = 0.f, d = 0.f;
#pragma unroll
    for (int c = 0; c < 8; c++) {
        float v = hp[c];
        s += v * a_src[h * 8 + c];
        d += v * a_dst[h * 8 + c];
    }
    es[i] = s;
    ed[i] = d;
}

// ---------------- CSR build ----------------
__global__ void deg_kernel(const int* __restrict__ ei, int* __restrict__ deg) {
    int i = blockIdx.x * blockDim.x + threadIdx.x;
    if (i >= NB * NE) return;
    int b = i / NE, e = i - b * NE;
    int dst = ei[(size_t)b * 2 * NE + NE + e];
    atomicAdd(deg + b * NN + dst, 1);
}

__global__ __launch_bounds__(1024) void scan_kernel(const int* __restrict__ deg,
                                                    int* __restrict__ rowptr,
                                                    int* __restrict__ cursor) {
    const int b = blockIdx.x;
    const int* d = deg + b * NN;
    int* rp = rowptr + b * (NN + 1);
    int* cur = cursor + b * NN;
    __shared__ int s[1024];
    __shared__ int run;
    if (threadIdx.x == 0) run = 0;
    __syncthreads();
    for (int base = 0; base < NN; base += 1024) {
        int i = base + threadIdx.x;
        int v = (i < NN) ? d[i] : 0;
        s[threadIdx.x] = v;
        __syncthreads();
        int val = v;
        for (int off = 1; off < 1024; off <<= 1) {
            int t = (threadIdx.x >= off) ? s[threadIdx.x - off] : 0;
            __syncthreads();
            val += t;
            s[threadIdx.x] = val;
            __syncthreads();
        }
        int excl = run + val - v;
        if (i < NN) { rp[i] = excl; cur[i] = excl; }
        __syncthreads();
        if (threadIdx.x == 0) run += s[1023];
        __syncthreads();
    }
    if (threadIdx.x == 0) rp[NN] = run;
}

__global__ void scatter_kernel(const int* __restrict__ ei, int* __restrict__ cursor,
                               int* __restrict__ col) {
    int i = blockIdx.x * blockDim.x + threadIdx.x;
    if (i >= NB * NE) return;
    int b = i / NE, e = i - b * NE;
    int src = ei[(size_t)b * 2 * NE + e];
    int dst = ei[(size_t)b * 2 * NE + NE + e];
    int pos = atomicAdd(cursor + b * NN + dst, 1);
    col[(size_t)b * NE + pos] = src;
}

// ---------------- layer-1 aggregate + ELU + layer-2 node transforms ----------------
// one wave per (b, dst node); lane = head*8 + channel
__global__ __launch_bounds__(256) void agg1_kernel(
    const float* __restrict__ h1, const float* __restrict__ es, const float* __restrict__ ed,
    const float* __restrict__ b1, const float* __restrict__ W2, const float* __restrict__ a2s,
    const float* __restrict__ a2d, const int* __restrict__ rowptr, const int* __restrict__ col,
    float* __restrict__ h2, float* __restrict__ es2, float* __restrict__ ed2) {
    int w = blockIdx.x * 4 + (threadIdx.x >> 6);
    if (w >= NB * NN) return;
    const int lane = threadIdx.x & 63;
    const int b = w / NN;
    const int n = w - b * NN;
    const int head = lane >> 3;
    const size_t nb = (size_t)b * NN;

    const float edv = ed[(nb + n) * 8 + head];
    float accv = 0.f, den = 0.f;
    {  // self loop
        float e = leaky(es[(nb + n) * 8 + head] + edv);
        float wv = __expf(e);
        den += wv;
        accv += wv * h1[(nb + n) * 64 + lane];
    }
    const int* cp = col + (size_t)b * NE;
    const int start = rowptr[b * (NN + 1) + n];
    const int end = rowptr[b * (NN + 1) + n + 1];
    for (int idx = start; idx < end; idx++) {
        int src = cp[idx];
        float e = leaky(es[(nb + src) * 8 + head] + edv);
        float wv = __expf(e);
        den += wv;
        accv += wv * h1[(nb + src) * 64 + lane];
    }
    float o = accv / (den + 1e-16f) + b1[lane];
    float g = o > 0.f ? o : expm1f(o);  // ELU

    // h2 = g(row of 64 across lanes) @ W2[64,7]; butterfly reductions
    float h2reg = 0.f;
#pragma unroll
    for (int c2 = 0; c2 < 7; c2++) {
        float v = g * W2[lane * 7 + c2];
#pragma unroll
        for (int off = 1; off < 64; off <<= 1) v += __shfl_xor(v, off, 64);
        if (lane == c2) h2reg = v;
    }
    if (lane < 8) h2[(nb + n) * 8 + lane] = (lane < 7) ? h2reg : 0.f;

    float p = (lane < 7) ? h2reg * a2s[lane] : 0.f;
#pragma unroll
    for (int off = 1; off < 64; off <<= 1) p += __shfl_xor(p, off, 64);
    float q = (lane < 7) ? h2reg * a2d[lane] : 0.f;
#pragma unroll
    for (int off = 1; off < 64; off <<= 1) q += __shfl_xor(q, off, 64);
    if (lane == 0) {
        es2[nb + n] = p;
        ed2[nb + n] = q;
    }
}

// ---------------- layer-2 aggregate + log_softmax ----------------
__global__ void agg2_kernel(const float* __restrict__ h2, const float* __restrict__ es2,
                            const float* __restrict__ ed2, const float* __restrict__ b2,
                            const int* __restrict__ rowptr, const int* __restrict__ col,
                            float* __restrict__ out) {
    int i = blockIdx.x * blockDim.x + threadIdx.x;
    if (i >= NB * NN) return;
    const int b = i / NN;
    const int n = i - b * NN;
    const size_t nb = (size_t)b * NN;
    const float edv = ed2[nb + n];
    float acc0 = 0, acc1 = 0, acc2 = 0, acc3 = 0, acc4 = 0, acc5 = 0, acc6 = 0, den = 0;
    {  // self loop
        float e = leaky(es2[nb + n] + edv);
        float wv = __expf(e);
        den += wv;
        const float4 u0 = *(const float4*)&h2[(nb + n) * 8];
        const float4 u1 = *(const float4*)&h2[(nb + n) * 8 + 4];
        acc0 += wv * u0.x; acc1 += wv * u0.y; acc2 += wv * u0.z; acc3 += wv * u0.w;
        acc4 += wv * u1.x; acc5 += wv * u1.y; acc6 += wv * u1.z;
    }
    const int* cp = col + (size_t)b * NE;
    const int start = rowptr[b * (NN + 1) + n];
    const int end = rowptr[b * (NN + 1) + n + 1];
    for (int idx = start; idx < end; idx++) {
        int src = cp[idx];
        float e = leaky(es2[nb + src] + edv);
        float wv = __expf(e);
        den += wv;
        const float4 u0 = *(const float4*)&h2[(nb + src) * 8];
        const float4 u1 = *(const float4*)&h2[(nb + src) * 8 + 4];
        acc0 += wv * u0.x; acc1 += wv * u0.y; acc2 += wv * u0.z; acc3 += wv * u0.w;
        acc4 += wv * u1.x; acc5 += wv * u1.y; acc6 += wv * u1.z;
    }
    float inv = 1.f / (den + 1e-16f);
    float o[7];
    o[0] = acc0 * inv + b2[0]; o[1] = acc1 * inv + b2[1]; o[2] = acc2 * inv + b2[2];
    o[3] = acc3 * inv + b2[3]; o[4] = acc4 * inv + b2[4]; o[5] = acc5 * inv + b2[5];
    o[6] = acc6 * inv + b2[6];
    float m = o[0];
#pragma unroll
    for (int c = 1; c < 7; c++) m = fmaxf(m, o[c]);
    float s = 0.f;
#pragma unroll
    for (int c = 0; c < 7; c++) s += expf(o[c] - m);
    float lse = m + logf(s);
    float* op = out + ((size_t)b * NN + n) * 7;
#pragma unroll
    for (int c = 0; c < 7; c++) op[c] = o[c] - lse;
}

extern "C" void kernel_launch(void* const* d_in, const int* in_sizes, int n_in,
                              void* d_out, int out_size, void* d_ws, size_t ws_size,
                              hipStream_t stream) {
    const float* x = (const float*)d_in[0];
    const int* ei = (const int*)d_in[1];
    const float* W1 = (const float*)d_in[2];
    const float* a1s = (const float*)d_in[3];
    const float* a1d = (const float*)d_in[4];
    const float* b1 = (const float*)d_in[5];
    const float* W2 = (const float*)d_in[6];
    const float* a2s = (const float*)d_in[7];
    const float* a2d = (const float*)d_in[8];
    const float* b2 = (const float*)d_in[9];
    float* out = (float*)d_out;

    // workspace bump allocator (all chunks 256B aligned)
    char* ws = (char*)d_ws;
    size_t off = 0;
    auto alloc = [&](size_t bytes) {
        void* p = ws + off;
        off += (bytes + 255) & ~(size_t)255;
        return p;
    };
    float* h1 = (float*)alloc((size_t)NB * NN * 64 * 4);
    float* es1 = (float*)alloc((size_t)NB * NN * 8 * 4);
    float* ed1 = (float*)alloc((size_t)NB * NN * 8 * 4);
    float* h2 = (float*)alloc((size_t)NB * NN * 8 * 4);
    float* es2 = (float*)alloc((size_t)NB * NN * 4);
    float* ed2 = (float*)alloc((size_t)NB * NN * 4);
    int* rowptr = (int*)alloc((size_t)NB * (NN + 1) * 4);
    int* cursor = (int*)alloc((size_t)NB * NN * 4);
    int* deg = (int*)alloc((size_t)NB * NN * 4);
    int* col = (int*)alloc((size_t)NB * NE * 4);

    hipMemsetAsync(deg, 0, (size_t)NB * NN * 4, stream);

    dim3 ggrid((NN + 63) / 64, NB);
    gemm1_kernel<<<ggrid, 256, 0, stream>>>(x, W1, h1);

    coef1_kernel<<<(NB * NN * 8 + 255) / 256, 256, 0, stream>>>(h1, a1s, a1d, es1, ed1);

    deg_kernel<<<(NB * NE + 255) / 256, 256, 0, stream>>>(ei, deg);
    scan_kernel<<<NB, 1024, 0, stream>>>(deg, rowptr, cursor);
    scatter_kernel<<<(NB * NE + 255) / 256, 256, 0, stream>>>(ei, cursor, col);

    agg1_kernel<<<(NB * NN + 3) / 4, 256, 0, stream>>>(h1, es1, ed1, b1, W2, a2s, a2d,
                                                       rowptr, col, h2, es2, ed2);
    agg2_kernel<<<(NB * NN + 255) / 256, 256, 0, stream>>>(h2, es2, ed2, b2, rowptr, col, out);
}

// Round 2
// 1242.755 us; speedup vs baseline: 1.4635x; 1.4635x over previous
//
#include <hip/hip_runtime.h>
#include <hip/hip_bf16.h>
#include <math.h>

#define NB 2
#define NN 50000
#define NE 800000
#define FIN 1433
#define KPAD 1440   // FIN padded to multiple of 32 (zeros)
#define HD 64
#define C2c 7
#define NCHUNK 196  // ceil(NN/256)

typedef __attribute__((ext_vector_type(8))) short short8;   // 8 x bf16
typedef __attribute__((ext_vector_type(4))) float f32x4;
typedef f32x4 __attribute__((aligned(4))) f32x4u;           // 4B-aligned vector load

static __device__ __forceinline__ float leaky(float e) { return e > 0.f ? e : 0.2f * e; }

static __device__ __forceinline__ short bf16r(float f) {
    __hip_bfloat16 h = __float2bfloat16(f);
    return *reinterpret_cast<short*>(&h);
}

// ---------------- W1 transpose + bf16 + K-pad: Bt[c][k] ----------------
__global__ __launch_bounds__(256) void w1t_kernel(const float* __restrict__ W,
                                                  short* __restrict__ Bt) {
    int i = blockIdx.x * 256 + threadIdx.x;  // over 64*KPAD
    if (i >= 64 * KPAD) return;
    int c = i / KPAD, k = i - c * KPAD;
    float v = (k < FIN) ? W[k * 64 + c] : 0.f;
    Bt[i] = bf16r(v);
}

// ---------------- GEMM1: h1 = x @ W1 via MFMA, no LDS, no barriers ----------------
// block = 256 thr = 4 waves; block tile = 128 rows x 64 cols; wave = 32 rows.
__global__ __launch_bounds__(256) void gemm1_mfma(const float* __restrict__ x,
                                                  const short* __restrict__ Bt,
                                                  float* __restrict__ h1) {
    const int b = blockIdx.y;
    const int wave = threadIdx.x >> 6;
    const int lane = threadIdx.x & 63;
    const int m = lane & 15;       // A row within 16-tile / D col within 16-tile
    const int quad = lane >> 4;    // k-offset group / D row group
    const int row0 = blockIdx.x * 128 + wave * 32;

    const float* xb = x + (size_t)b * NN * FIN;
    float* hb = h1 + (size_t)b * NN * HD;

    int r0 = row0 + m;
    int r1 = row0 + 16 + m;
    int r0c = r0 < NN ? r0 : NN - 1;  // clamp for safe loads; stores guarded
    int r1c = r1 < NN ? r1 : NN - 1;
    const float* a0p = xb + (size_t)r0c * FIN + quad * 8;
    const float* a1p = xb + (size_t)r1c * FIN + quad * 8;
    const short* btp = Bt + quad * 8 + (size_t)m * KPAD;  // + n*16*KPAD + kt

    f32x4 acc[2][4];
#pragma unroll
    for (int t = 0; t < 2; t++)
#pragma unroll
        for (int n = 0; n < 4; n++) acc[t][n] = (f32x4){0.f, 0.f, 0.f, 0.f};

    // 44 full K-chunks: k up to 1376+quad*8+7 <= 1407 < 1433, always in-row
    for (int kt = 0; kt < 1408; kt += 32) {
        f32x4 af00 = *(const f32x4u*)(a0p + kt);
        f32x4 af01 = *(const f32x4u*)(a0p + kt + 4);
        f32x4 af10 = *(const f32x4u*)(a1p + kt);
        f32x4 af11 = *(const f32x4u*)(a1p + kt + 4);
        short8 fa0, fa1;
        fa0[0] = bf16r(af00[0]); fa0[1] = bf16r(af00[1]); fa0[2] = bf16r(af00[2]); fa0[3] = bf16r(af00[3]);
        fa0[4] = bf16r(af01[0]); fa0[5] = bf16r(af01[1]); fa0[6] = bf16r(af01[2]); fa0[7] = bf16r(af01[3]);
        fa1[0] = bf16r(af10[0]); fa1[1] = bf16r(af10[1]); fa1[2] = bf16r(af10[2]); fa1[3] = bf16r(af10[3]);
        fa1[4] = bf16r(af11[0]); fa1[5] = bf16r(af11[1]); fa1[6] = bf16r(af11[2]); fa1[7] = bf16r(af11[3]);
#pragma unroll
        for (int n = 0; n < 4; n++) {
            short8 fb = *(const short8*)(btp + (size_t)n * 16 * KPAD + kt);
            acc[0][n] = __builtin_amdgcn_mfma_f32_16x16x32_bf16(fa0, fb, acc[0][n], 0, 0, 0);
            acc[1][n] = __builtin_amdgcn_mfma_f32_16x16x32_bf16(fa1, fb, acc[1][n], 0, 0, 0);
        }
    }
    {  // tail chunk kt=1408, guarded element loads (k >= FIN -> 0; Bt is 0 there too)
        short8 fa0, fa1;
#pragma unroll
        for (int j = 0; j < 8; j++) {
            int k = 1408 + quad * 8 + j;
            fa0[j] = bf16r(k < FIN ? a0p[1408 + j] : 0.f);
            fa1[j] = bf16r(k < FIN ? a1p[1408 + j] : 0.f);
        }
#pragma unroll
        for (int n = 0; n < 4; n++) {
            short8 fb = *(const short8*)(btp + (size_t)n * 16 * KPAD + 1408);
            acc[0][n] = __builtin_amdgcn_mfma_f32_16x16x32_bf16(fa0, fb, acc[0][n], 0, 0, 0);
            acc[1][n] = __builtin_amdgcn_mfma_f32_16x16x32_bf16(fa1, fb, acc[1][n], 0, 0, 0);
        }
    }
    // D layout: col = lane&15 (=m), row = quad*4 + reg
#pragma unroll
    for (int t = 0; t < 2; t++) {
#pragma unroll
        for (int r = 0; r < 4; r++) {
            int row = row0 + t * 16 + quad * 4 + r;
            if (row < NN) {
#pragma unroll
                for (int n = 0; n < 4; n++) hb[(size_t)row * HD + n * 16 + m] = acc[t][n][r];
            }
        }
    }
}

// ---------------- per-node attention coefficients, layer 1 ----------------
__global__ void coef1_kernel(const float* __restrict__ h1, const float* __restrict__ a_src,
                             const float* __restrict__ a_dst, float* __restrict__ es,
                             float* __restrict__ ed) {
    int i = blockIdx.x * blockDim.x + threadIdx.x;  // over B*N*8
    if (i >= NB * NN * 8) return;
    int h = i & 7;
    int n = i >> 3;
    const float* hp = h1 + (size_t)n * 64 + h * 8;
    float s = 0.f, d = 0.f;
#pragma unroll
    for (int c = 0; c < 8; c++) {
        float v = hp[c];
        s += v * a_src[h * 8 + c];
        d += v * a_dst[h * 8 + c];
    }
    es[i] = s;
    ed[i] = d;
}

// ---------------- CSR build ----------------
__global__ void deg_kernel(const int* __restrict__ ei, int* __restrict__ deg) {
    int i = blockIdx.x * blockDim.x + threadIdx.x;
    if (i >= NB * NE) return;
    int b = i / NE, e = i - b * NE;
    int dst = ei[(size_t)b * 2 * NE + NE + e];
    atomicAdd(deg + b * NN + dst, 1);
}

__global__ __launch_bounds__(256) void scan1_kernel(const int* __restrict__ deg,
                                                    int* __restrict__ rowptr,
                                                    int* __restrict__ bsum) {
    const int b = blockIdx.y, th = threadIdx.x;
    const int i = blockIdx.x * 256 + th;
    __shared__ int s[256];
    int v = (i < NN) ? deg[b * NN + i] : 0;
    s[th] = v;
    __syncthreads();
    int val = v;
    for (int off = 1; off < 256; off <<= 1) {
        int t = (th >= off) ? s[th - off] : 0;
        __syncthreads();
        val += t;
        s[th] = val;
        __syncthreads();
    }
    if (i < NN) rowptr[b * (NN + 1) + i] = val - v;  // chunk-local exclusive
    if (th == 255) bsum[b * NCHUNK + blockIdx.x] = val;
}

__global__ __launch_bounds__(256) void scan2_kernel(const int* __restrict__ bsum,
                                                    int* __restrict__ boff,
                                                    int* __restrict__ rowptr) {
    const int b = blockIdx.x, th = threadIdx.x;
    __shared__ int s[256];
    int v = (th < NCHUNK) ? bsum[b * NCHUNK + th] : 0;
    s[th] = v;
    __syncthreads();
    int val = v;
    for (int off = 1; off < 256; off <<= 1) {
        int t = (th >= off) ? s[th - off] : 0;
        __syncthreads();
        val += t;
        s[th] = val;
        __syncthreads();
    }
    if (th < NCHUNK) boff[b * NCHUNK + th] = val - v;
    if (th == 255) rowptr[b * (NN + 1) + NN] = val;  // grand total (== NE)
}

__global__ __launch_bounds__(256) void scan3_kernel(const int* __restrict__ boff,
                                                    int* __restrict__ rowptr,
                                                    int* __restrict__ cursor) {
    const int b = blockIdx.y;
    const int i = blockIdx.x * 256 + threadIdx.x;
    if (i >= NN) return;
    int r = rowptr[b * (NN + 1) + i] + boff[b * NCHUNK + blockIdx.x];
    rowptr[b * (NN + 1) + i] = r;
    cursor[b * NN + i] = r;
}

__global__ void scatter_kernel(const int* __restrict__ ei, int* __restrict__ cursor,
                               int* __restrict__ col) {
    int i = blockIdx.x * blockDim.x + threadIdx.x;
    if (i >= NB * NE) return;
    int b = i / NE, e = i - b * NE;
    int src = ei[(size_t)b * 2 * NE + e];
    int dst = ei[(size_t)b * 2 * NE + NE + e];
    int pos = atomicAdd(cursor + b * NN + dst, 1);
    col[(size_t)b * NE + pos] = src;
}

// ---------------- layer-1 aggregate + ELU + layer-2 node transforms ----------------
// one wave per (b, dst node); lane = head*8 + channel
__global__ __launch_bounds__(256) void agg1_kernel(
    const float* __restrict__ h1, const float* __restrict__ es, const float* __restrict__ ed,
    const float* __restrict__ b1, const float* __restrict__ W2, const float* __restrict__ a2s,
    const float* __restrict__ a2d, const int* __restrict__ rowptr, const int* __restrict__ col,
    float* __restrict__ h2, float* __restrict__ es2, float* __restrict__ ed2) {
    int w = blockIdx.x * 4 + (threadIdx.x >> 6);
    if (w >= NB * NN) return;
    const int lane = threadIdx.x & 63;
    const int b = w / NN;
    const int n = w - b * NN;
    const int head = lane >> 3;
    const size_t nb = (size_t)b * NN;

    const float edv = ed[(nb + n) * 8 + head];
    float accv = 0.f, den = 0.f;
    {  // self loop
        float e = leaky(es[(nb + n) * 8 + head] + edv);
        float wv = __expf(e);
        den += wv;
        accv += wv * h1[(nb + n) * 64 + lane];
    }
    const int* cp = col + (size_t)b * NE;
    const int start = rowptr[b * (NN + 1) + n];
    const int end = rowptr[b * (NN + 1) + n + 1];
    for (int idx = start; idx < end; idx++) {
        int src = cp[idx];
        float e = leaky(es[(nb + src) * 8 + head] + edv);
        float wv = __expf(e);
        den += wv;
        accv += wv * h1[(nb + src) * 64 + lane];
    }
    float o = accv / (den + 1e-16f) + b1[lane];
    float g = o > 0.f ? o : expm1f(o);  // ELU

    // h2 = g(row of 64 across lanes) @ W2[64,7]; butterfly reductions
    float h2reg = 0.f;
#pragma unroll
    for (int c2 = 0; c2 < 7; c2++) {
        float v = g * W2[lane * 7 + c2];
#pragma unroll
        for (int off = 1; off < 64; off <<= 1) v += __shfl_xor(v, off, 64);
        if (lane == c2) h2reg = v;
    }
    if (lane < 8) h2[(nb + n) * 8 + lane] = (lane < 7) ? h2reg : 0.f;

    float p = (lane < 7) ? h2reg * a2s[lane] : 0.f;
#pragma unroll
    for (int off = 1; off < 64; off <<= 1) p += __shfl_xor(p, off, 64);
    float q = (lane < 7) ? h2reg * a2d[lane] : 0.f;
#pragma unroll
    for (int off = 1; off < 64; off <<= 1) q += __shfl_xor(q, off, 64);
    if (lane == 0) {
        es2[nb + n] = p;
        ed2[nb + n] = q;
    }
}

// ---------------- layer-2 aggregate + log_softmax ----------------
__global__ void agg2_kernel(const float* __restrict__ h2, const float* __restrict__ es2,
                            const float* __restrict__ ed2, const float* __restrict__ b2,
                            const int* __restrict__ rowptr, const int* __restrict__ col,
                            float* __restrict__ out) {
    int i = blockIdx.x * blockDim.x + threadIdx.x;
    if (i >= NB * NN) return;
    const int b = i / NN;
    const int n = i - b * NN;
    const size_t nb = (size_t)b * NN;
    const float edv = ed2[nb + n];
    float acc0 = 0, acc1 = 0, acc2 = 0, acc3 = 0, acc4 = 0, acc5 = 0, acc6 = 0, den = 0;
    {  // self loop
        float e = leaky(es2[nb + n] + edv);
        float wv = __expf(e);
        den += wv;
        const float4 u0 = *(const float4*)&h2[(nb + n) * 8];
        const float4 u1 = *(const float4*)&h2[(nb + n) * 8 + 4];
        acc0 += wv * u0.x; acc1 += wv * u0.y; acc2 += wv * u0.z; acc3 += wv * u0.w;
        acc4 += wv * u1.x; acc5 += wv * u1.y; acc6 += wv * u1.z;
    }
    const int* cp = col + (size_t)b * NE;
    const int start = rowptr[b * (NN + 1) + n];
    const int end = rowptr[b * (NN + 1) + n + 1];
    for (int idx = start; idx < end; idx++) {
        int src = cp[idx];
        float e = leaky(es2[nb + src] + edv);
        float wv = __expf(e);
        den += wv;
        const float4 u0 = *(const float4*)&h2[(nb + src) * 8];
        const float4 u1 = *(const float4*)&h2[(nb + src) * 8 + 4];
        acc0 += wv * u0.x; acc1 += wv * u0.y; acc2 += wv * u0.z; acc3 += wv * u0.w;
        acc4 += wv * u1.x; acc5 += wv * u1.y; acc6 += wv * u1.z;
    }
    float inv = 1.f / (den + 1e-16f);
    float o[7];
    o[0] = acc0 * inv + b2[0]; o[1] = acc1 * inv + b2[1]; o[2] = acc2 * inv + b2[2];
    o[3] = acc3 * inv + b2[3]; o[4] = acc4 * inv + b2[4]; o[5] = acc5 * inv + b2[5];
    o[6] = acc6 * inv + b2[6];
    float m = o[0];
#pragma unroll
    for (int c = 1; c < 7; c++) m = fmaxf(m, o[c]);
    float s = 0.f;
#pragma unroll
    for (int c = 0; c < 7; c++) s += expf(o[c] - m);
    float lse = m + logf(s);
    float* op = out + ((size_t)b * NN + n) * 7;
#pragma unroll
    for (int c = 0; c < 7; c++) op[c] = o[c] - lse;
}

extern "C" void kernel_launch(void* const* d_in, const int* in_sizes, int n_in,
                              void* d_out, int out_size, void* d_ws, size_t ws_size,
                              hipStream_t stream) {
    const float* x = (const float*)d_in[0];
    const int* ei = (const int*)d_in[1];
    const float* W1 = (const float*)d_in[2];
    const float* a1s = (const float*)d_in[3];
    const float* a1d = (const float*)d_in[4];
    const float* b1 = (const float*)d_in[5];
    const float* W2 = (const float*)d_in[6];
    const float* a2s = (const float*)d_in[7];
    const float* a2d = (const float*)d_in[8];
    const float* b2 = (const float*)d_in[9];
    float* out = (float*)d_out;

    char* ws = (char*)d_ws;
    size_t off = 0;
    auto alloc = [&](size_t bytes) {
        void* p = ws + off;
        off += (bytes + 255) & ~(size_t)255;
        return p;
    };
    float* h1 = (float*)alloc((size_t)NB * NN * 64 * 4);
    float* es1 = (float*)alloc((size_t)NB * NN * 8 * 4);
    float* ed1 = (float*)alloc((size_t)NB * NN * 8 * 4);
    float* h2 = (float*)alloc((size_t)NB * NN * 8 * 4);
    float* es2 = (float*)alloc((size_t)NB * NN * 4);
    float* ed2 = (float*)alloc((size_t)NB * NN * 4);
    int* rowptr = (int*)alloc((size_t)NB * (NN + 1) * 4);
    int* cursor = (int*)alloc((size_t)NB * NN * 4);
    int* deg = (int*)alloc((size_t)NB * NN * 4);
    int* col = (int*)alloc((size_t)NB * NE * 4);
    short* Bt = (short*)alloc((size_t)64 * KPAD * 2);
    int* bsum = (int*)alloc((size_t)NB * NCHUNK * 4);
    int* boff = (int*)alloc((size_t)NB * NCHUNK * 4);

    hipMemsetAsync(deg, 0, (size_t)NB * NN * 4, stream);

    w1t_kernel<<<(64 * KPAD + 255) / 256, 256, 0, stream>>>(W1, Bt);

    dim3 ggrid((NN + 127) / 128, NB);
    gemm1_mfma<<<ggrid, 256, 0, stream>>>(x, Bt, h1);

    coef1_kernel<<<(NB * NN * 8 + 255) / 256, 256, 0, stream>>>(h1, a1s, a1d, es1, ed1);

    deg_kernel<<<(NB * NE + 255) / 256, 256, 0, stream>>>(ei, deg);
    dim3 sgrid(NCHUNK, NB);
    scan1_kernel<<<sgrid, 256, 0, stream>>>(deg, rowptr, bsum);
    scan2_kernel<<<NB, 256, 0, stream>>>(bsum, boff, rowptr);
    scan3_kernel<<<sgrid, 256, 0, stream>>>(boff, rowptr, cursor);
    scatter_kernel<<<(NB * NE + 255) / 256, 256, 0, stream>>>(ei, cursor, col);

    agg1_kernel<<<(NB * NN + 3) / 4, 256, 0, stream>>>(h1, es1, ed1, b1, W2, a2s, a2d,
                                                       rowptr, col, h2, es2, ed2);
    agg2_kernel<<<(NB * NN + 255) / 256, 256, 0, stream>>>(h2, es2, ed2, b2, rowptr, col, out);
}

// Round 3
// 1223.783 us; speedup vs baseline: 1.4862x; 1.0155x over previous
//
#include <hip/hip_runtime.h>
#include <hip/hip_bf16.h>
#include <math.h>

#define NB 2
#define NN 50000
#define NE 800000
#define FIN 1433
#define KPAD 1440   // FIN padded to multiple of 32 (zeros)
#define HD 64
#define C2c 7
#define NCHUNK 196  // ceil(NN/256)

typedef __attribute__((ext_vector_type(8))) short short8;   // 8 x bf16
typedef __attribute__((ext_vector_type(4))) float f32x4;
typedef f32x4 __attribute__((aligned(4))) f32x4u;           // 4B-aligned vector load

static __device__ __forceinline__ float leaky(float e) { return e > 0.f ? e : 0.2f * e; }

static __device__ __forceinline__ short bf16r(float f) {
    __hip_bfloat16 h = __float2bfloat16(f);
    return *reinterpret_cast<short*>(&h);
}
static __device__ __forceinline__ float bf2f(short s) {
    unsigned u = ((unsigned)(unsigned short)s) << 16;
    return __uint_as_float(u);
}

// ---------------- W1 transpose + bf16 + K-pad: Bt[c][k] ----------------
__global__ __launch_bounds__(256) void w1t_kernel(const float* __restrict__ W,
                                                  short* __restrict__ Bt) {
    int i = blockIdx.x * 256 + threadIdx.x;  // over 64*KPAD
    if (i >= 64 * KPAD) return;
    int c = i / KPAD, k = i - c * KPAD;
    float v = (k < FIN) ? W[k * 64 + c] : 0.f;
    Bt[i] = bf16r(v);
}

// ---------------- GEMM1: h1 = x @ W1 via MFMA, no LDS, no barriers ----------------
// block = 256 thr = 4 waves; block tile = 128 rows x 64 cols; wave = 32 rows.
// h1 written as bf16 (consumers: coef1 + agg1 gathers).
__global__ __launch_bounds__(256) void gemm1_mfma(const float* __restrict__ x,
                                                  const short* __restrict__ Bt,
                                                  short* __restrict__ h1b) {
    const int b = blockIdx.y;
    const int wave = threadIdx.x >> 6;
    const int lane = threadIdx.x & 63;
    const int m = lane & 15;       // A row within 16-tile / D col within 16-tile
    const int quad = lane >> 4;    // k-offset group / D row group
    const int row0 = blockIdx.x * 128 + wave * 32;

    const float* xb = x + (size_t)b * NN * FIN;
    short* hb = h1b + (size_t)b * NN * HD;

    int r0 = row0 + m;
    int r1 = row0 + 16 + m;
    int r0c = r0 < NN ? r0 : NN - 1;  // clamp for safe loads; stores guarded
    int r1c = r1 < NN ? r1 : NN - 1;
    const float* a0p = xb + (size_t)r0c * FIN + quad * 8;
    const float* a1p = xb + (size_t)r1c * FIN + quad * 8;
    const short* btp = Bt + quad * 8 + (size_t)m * KPAD;  // + n*16*KPAD + kt

    f32x4 acc[2][4];
#pragma unroll
    for (int t = 0; t < 2; t++)
#pragma unroll
        for (int n = 0; n < 4; n++) acc[t][n] = (f32x4){0.f, 0.f, 0.f, 0.f};

    // 44 full K-chunks: k up to 1376+quad*8+7 <= 1407 < 1433, always in-row
    for (int kt = 0; kt < 1408; kt += 32) {
        f32x4 af00 = *(const f32x4u*)(a0p + kt);
        f32x4 af01 = *(const f32x4u*)(a0p + kt + 4);
        f32x4 af10 = *(const f32x4u*)(a1p + kt);
        f32x4 af11 = *(const f32x4u*)(a1p + kt + 4);
        short8 fa0, fa1;
        fa0[0] = bf16r(af00[0]); fa0[1] = bf16r(af00[1]); fa0[2] = bf16r(af00[2]); fa0[3] = bf16r(af00[3]);
        fa0[4] = bf16r(af01[0]); fa0[5] = bf16r(af01[1]); fa0[6] = bf16r(af01[2]); fa0[7] = bf16r(af01[3]);
        fa1[0] = bf16r(af10[0]); fa1[1] = bf16r(af10[1]); fa1[2] = bf16r(af10[2]); fa1[3] = bf16r(af10[3]);
        fa1[4] = bf16r(af11[0]); fa1[5] = bf16r(af11[1]); fa1[6] = bf16r(af11[2]); fa1[7] = bf16r(af11[3]);
#pragma unroll
        for (int n = 0; n < 4; n++) {
            short8 fb = *(const short8*)(btp + (size_t)n * 16 * KPAD + kt);
            acc[0][n] = __builtin_amdgcn_mfma_f32_16x16x32_bf16(fa0, fb, acc[0][n], 0, 0, 0);
            acc[1][n] = __builtin_amdgcn_mfma_f32_16x16x32_bf16(fa1, fb, acc[1][n], 0, 0, 0);
        }
    }
    {  // tail chunk kt=1408, guarded element loads (k >= FIN -> 0; Bt is 0 there too)
        short8 fa0, fa1;
#pragma unroll
        for (int j = 0; j < 8; j++) {
            int k = 1408 + quad * 8 + j;
            fa0[j] = bf16r(k < FIN ? a0p[1408 + j] : 0.f);
            fa1[j] = bf16r(k < FIN ? a1p[1408 + j] : 0.f);
        }
#pragma unroll
        for (int n = 0; n < 4; n++) {
            short8 fb = *(const short8*)(btp + (size_t)n * 16 * KPAD + 1408);
            acc[0][n] = __builtin_amdgcn_mfma_f32_16x16x32_bf16(fa0, fb, acc[0][n], 0, 0, 0);
            acc[1][n] = __builtin_amdgcn_mfma_f32_16x16x32_bf16(fa1, fb, acc[1][n], 0, 0, 0);
        }
    }
    // D layout: col = lane&15 (=m), row = quad*4 + reg
#pragma unroll
    for (int t = 0; t < 2; t++) {
#pragma unroll
        for (int r = 0; r < 4; r++) {
            int row = row0 + t * 16 + quad * 4 + r;
            if (row < NN) {
#pragma unroll
                for (int n = 0; n < 4; n++) hb[(size_t)row * HD + n * 16 + m] = bf16r(acc[t][n][r]);
            }
        }
    }
}

// ---------------- per-node attention coefficients, layer 1 ----------------
__global__ void coef1_kernel(const short* __restrict__ h1b, const float* __restrict__ a_src,
                             const float* __restrict__ a_dst, float* __restrict__ es,
                             float* __restrict__ ed) {
    int i = blockIdx.x * blockDim.x + threadIdx.x;  // over B*N*8
    if (i >= NB * NN * 8) return;
    int h = i & 7;
    int n = i >> 3;
    const short8 hv = *(const short8*)(h1b + (size_t)n * 64 + h * 8);
    float s = 0.f, d = 0.f;
#pragma unroll
    for (int c = 0; c < 8; c++) {
        float v = bf2f(hv[c]);
        s += v * a_src[h * 8 + c];
        d += v * a_dst[h * 8 + c];
    }
    es[i] = s;
    ed[i] = d;
}

// ---------------- CSR build ----------------
__global__ void deg_kernel(const int* __restrict__ ei, int* __restrict__ deg) {
    int i = blockIdx.x * blockDim.x + threadIdx.x;
    if (i >= NB * NE) return;
    int b = i / NE, e = i - b * NE;
    int dst = ei[(size_t)b * 2 * NE + NE + e];
    atomicAdd(deg + b * NN + dst, 1);
}

__global__ __launch_bounds__(256) void scan1_kernel(const int* __restrict__ deg,
                                                    int* __restrict__ rowptr,
                                                    int* __restrict__ bsum) {
    const int b = blockIdx.y, th = threadIdx.x;
    const int i = blockIdx.x * 256 + th;
    __shared__ int s[256];
    int v = (i < NN) ? deg[b * NN + i] : 0;
    s[th] = v;
    __syncthreads();
    int val = v;
    for (int off = 1; off < 256; off <<= 1) {
        int t = (th >= off) ? s[th - off] : 0;
        __syncthreads();
        val += t;
        s[th] = val;
        __syncthreads();
    }
    if (i < NN) rowptr[b * (NN + 1) + i] = val - v;  // chunk-local exclusive
    if (th == 255) bsum[b * NCHUNK + blockIdx.x] = val;
}

__global__ __launch_bounds__(256) void scan2_kernel(const int* __restrict__ bsum,
                                                    int* __restrict__ boff,
                                                    int* __restrict__ rowptr) {
    const int b = blockIdx.x, th = threadIdx.x;
    __shared__ int s[256];
    int v = (th < NCHUNK) ? bsum[b * NCHUNK + th] : 0;
    s[th] = v;
    __syncthreads();
    int val = v;
    for (int off = 1; off < 256; off <<= 1) {
        int t = (th >= off) ? s[th - off] : 0;
        __syncthreads();
        val += t;
        s[th] = val;
        __syncthreads();
    }
    if (th < NCHUNK) boff[b * NCHUNK + th] = val - v;
    if (th == 255) rowptr[b * (NN + 1) + NN] = val;  // grand total (== NE)
}

__global__ __launch_bounds__(256) void scan3_kernel(const int* __restrict__ boff,
                                                    int* __restrict__ rowptr,
                                                    int* __restrict__ cursor) {
    const int b = blockIdx.y;
    const int i = blockIdx.x * 256 + threadIdx.x;
    if (i >= NN) return;
    int r = rowptr[b * (NN + 1) + i] + boff[b * NCHUNK + blockIdx.x];
    rowptr[b * (NN + 1) + i] = r;
    cursor[b * NN + i] = r;
}

__global__ void scatter_kernel(const int* __restrict__ ei, int* __restrict__ cursor,
                               int* __restrict__ col) {
    int i = blockIdx.x * blockDim.x + threadIdx.x;
    if (i >= NB * NE) return;
    int b = i / NE, e = i - b * NE;
    int src = ei[(size_t)b * 2 * NE + e];
    int dst = ei[(size_t)b * 2 * NE + NE + e];
    int pos = atomicAdd(cursor + b * NN + dst, 1);
    col[(size_t)b * NE + pos] = src;
}

// ---------------- layer-1 aggregate + ELU + layer-2 node transforms ----------------
// one wave per (b, dst node); 8 subwaves x 8 lanes; subwave s handles edge idx+s,
// lane's head cg = lane&7 covers channels cg*8..cg*8+7 via one 16B bf16 load.
__global__ __launch_bounds__(256) void agg1_kernel(
    const short* __restrict__ h1b, const float* __restrict__ es, const float* __restrict__ ed,
    const float* __restrict__ b1, const float* __restrict__ W2, const float* __restrict__ a2s,
    const float* __restrict__ a2d, const int* __restrict__ rowptr, const int* __restrict__ col,
    float* __restrict__ h2, float* __restrict__ es2, float* __restrict__ ed2) {
    int w = blockIdx.x * 4 + (threadIdx.x >> 6);
    if (w >= NB * NN) return;
    const int lane = threadIdx.x & 63;
    const int s = lane >> 3;   // subwave (edge slot)
    const int cg = lane & 7;   // head / channel group
    const int b = w / NN;
    const int n = w - b * NN;
    const size_t nb = (size_t)b * NN;

    const float edv = ed[(nb + n) * 8 + cg];
    float den = 0.f;
    float acc[8];
#pragma unroll
    for (int j = 0; j < 8; j++) acc[j] = 0.f;

    if (s == 0) {  // self loop handled by subwave 0
        float e = leaky(es[(nb + n) * 8 + cg] + edv);
        float wv = __expf(e);
        den = wv;
        const short8 hv = *(const short8*)(h1b + (nb + n) * 64 + cg * 8);
#pragma unroll
        for (int j = 0; j < 8; j++) acc[j] = wv * bf2f(hv[j]);
    }

    const int* cp = col + (size_t)b * NE;
    const int start = rowptr[b * (NN + 1) + n];
    const int end = rowptr[b * (NN + 1) + n + 1];
    for (int idx = start + s; idx < end; idx += 8) {
        int src = cp[idx];
        float e = leaky(es[(nb + src) * 8 + cg] + edv);
        float wv = __expf(e);
        den += wv;
        const short8 hv = *(const short8*)(h1b + (nb + src) * 64 + cg * 8);
#pragma unroll
        for (int j = 0; j < 8; j++) acc[j] += wv * bf2f(hv[j]);
    }

    // combine the 8 subwaves (xor over lane bits 3,4,5)
#pragma unroll
    for (int off = 8; off < 64; off <<= 1) {
        den += __shfl_xor(den, off, 64);
#pragma unroll
        for (int j = 0; j < 8; j++) acc[j] += __shfl_xor(acc[j], off, 64);
    }

    const float inv = 1.f / (den + 1e-16f);
    float g[8];
#pragma unroll
    for (int j = 0; j < 8; j++) {
        float o = acc[j] * inv + b1[cg * 8 + j];
        g[j] = o > 0.f ? o : expm1f(o);  // ELU
    }

    // layer-2 node transform: h2[c2] = sum_c g_full[c] * W2[c][c2]
    float p[7];
#pragma unroll
    for (int c2 = 0; c2 < 7; c2++) {
        float v = 0.f;
#pragma unroll
        for (int j = 0; j < 8; j++) v += g[j] * W2[(cg * 8 + j) * 7 + c2];
        p[c2] = v;
    }
#pragma unroll
    for (int off = 1; off < 8; off <<= 1) {
#pragma unroll
        for (int c2 = 0; c2 < 7; c2++) p[c2] += __shfl_xor(p[c2], off, 64);
    }
    if (lane == 0) {
        float4 v0 = make_float4(p[0], p[1], p[2], p[3]);
        float4 v1 = make_float4(p[4], p[5], p[6], 0.f);
        *(float4*)&h2[(nb + n) * 8] = v0;
        *(float4*)&h2[(nb + n) * 8 + 4] = v1;
        float s2 = 0.f, d2 = 0.f;
#pragma unroll
        for (int c2 = 0; c2 < 7; c2++) {
            s2 += p[c2] * a2s[c2];
            d2 += p[c2] * a2d[c2];
        }
        es2[nb + n] = s2;
        ed2[nb + n] = d2;
    }
}

// ---------------- layer-2 aggregate + log_softmax ----------------
__global__ void agg2_kernel(const float* __restrict__ h2, const float* __restrict__ es2,
                            const float* __restrict__ ed2, const float* __restrict__ b2,
                            const int* __restrict__ rowptr, const int* __restrict__ col,
                            float* __restrict__ out) {
    int i = blockIdx.x * blockDim.x + threadIdx.x;
    if (i >= NB * NN) return;
    const int b = i / NN;
    const int n = i - b * NN;
    const size_t nb = (size_t)b * NN;
    const float edv = ed2[nb + n];
    float acc0 = 0, acc1 = 0, acc2 = 0, acc3 = 0, acc4 = 0, acc5 = 0, acc6 = 0, den = 0;
    {  // self loop
        float e = leaky(es2[nb + n] + edv);
        float wv = __expf(e);
        den += wv;
        const float4 u0 = *(const float4*)&h2[(nb + n) * 8];
        const float4 u1 = *(const float4*)&h2[(nb + n) * 8 + 4];
        acc0 += wv * u0.x; acc1 += wv * u0.y; acc2 += wv * u0.z; acc3 += wv * u0.w;
        acc4 += wv * u1.x; acc5 += wv * u1.y; acc6 += wv * u1.z;
    }
    const int* cp = col + (size_t)b * NE;
    const int start = rowptr[b * (NN + 1) + n];
    const int end = rowptr[b * (NN + 1) + n + 1];
    for (int idx = start; idx < end; idx++) {
        int src = cp[idx];
        float e = leaky(es2[nb + src] + edv);
        float wv = __expf(e);
        den += wv;
        const float4 u0 = *(const float4*)&h2[(nb + src) * 8];
        const float4 u1 = *(const float4*)&h2[(nb + src) * 8 + 4];
        acc0 += wv * u0.x; acc1 += wv * u0.y; acc2 += wv * u0.z; acc3 += wv * u0.w;
        acc4 += wv * u1.x; acc5 += wv * u1.y; acc6 += wv * u1.z;
    }
    float inv = 1.f / (den + 1e-16f);
    float o[7];
    o[0] = acc0 * inv + b2[0]; o[1] = acc1 * inv + b2[1]; o[2] = acc2 * inv + b2[2];
    o[3] = acc3 * inv + b2[3]; o[4] = acc4 * inv + b2[4]; o[5] = acc5 * inv + b2[5];
    o[6] = acc6 * inv + b2[6];
    float m = o[0];
#pragma unroll
    for (int c = 1; c < 7; c++) m = fmaxf(m, o[c]);
    float sum = 0.f;
#pragma unroll
    for (int c = 0; c < 7; c++) sum += expf(o[c] - m);
    float lse = m + logf(sum);
    float* op = out + ((size_t)b * NN + n) * 7;
#pragma unroll
    for (int c = 0; c < 7; c++) op[c] = o[c] - lse;
}

extern "C" void kernel_launch(void* const* d_in, const int* in_sizes, int n_in,
                              void* d_out, int out_size, void* d_ws, size_t ws_size,
                              hipStream_t stream) {
    const float* x = (const float*)d_in[0];
    const int* ei = (const int*)d_in[1];
    const float* W1 = (const float*)d_in[2];
    const float* a1s = (const float*)d_in[3];
    const float* a1d = (const float*)d_in[4];
    const float* b1 = (const float*)d_in[5];
    const float* W2 = (const float*)d_in[6];
    const float* a2s = (const float*)d_in[7];
    const float* a2d = (const float*)d_in[8];
    const float* b2 = (const float*)d_in[9];
    float* out = (float*)d_out;

    char* ws = (char*)d_ws;
    size_t off = 0;
    auto alloc = [&](size_t bytes) {
        void* p = ws + off;
        off += (bytes + 255) & ~(size_t)255;
        return p;
    };
    short* h1b = (short*)alloc((size_t)NB * NN * 64 * 2);
    float* es1 = (float*)alloc((size_t)NB * NN * 8 * 4);
    float* ed1 = (float*)alloc((size_t)NB * NN * 8 * 4);
    float* h2 = (float*)alloc((size_t)NB * NN * 8 * 4);
    float* es2 = (float*)alloc((size_t)NB * NN * 4);
    float* ed2 = (float*)alloc((size_t)NB * NN * 4);
    int* rowptr = (int*)alloc((size_t)NB * (NN + 1) * 4);
    int* cursor = (int*)alloc((size_t)NB * NN * 4);
    int* deg = (int*)alloc((size_t)NB * NN * 4);
    int* col = (int*)alloc((size_t)NB * NE * 4);
    short* Bt = (short*)alloc((size_t)64 * KPAD * 2);
    int* bsum = (int*)alloc((size_t)NB * NCHUNK * 4);
    int* boff = (int*)alloc((size_t)NB * NCHUNK * 4);

    hipMemsetAsync(deg, 0, (size_t)NB * NN * 4, stream);

    w1t_kernel<<<(64 * KPAD + 255) / 256, 256, 0, stream>>>(W1, Bt);

    dim3 ggrid((NN + 127) / 128, NB);
    gemm1_mfma<<<ggrid, 256, 0, stream>>>(x, Bt, h1b);

    coef1_kernel<<<(NB * NN * 8 + 255) / 256, 256, 0, stream>>>(h1b, a1s, a1d, es1, ed1);

    deg_kernel<<<(NB * NE + 255) / 256, 256, 0, stream>>>(ei, deg);
    dim3 sgrid(NCHUNK, NB);
    scan1_kernel<<<sgrid, 256, 0, stream>>>(deg, rowptr, bsum);
    scan2_kernel<<<NB, 256, 0, stream>>>(bsum, boff, rowptr);
    scan3_kernel<<<sgrid, 256, 0, stream>>>(boff, rowptr, cursor);
    scatter_kernel<<<(NB * NE + 255) / 256, 256, 0, stream>>>(ei, cursor, col);

    agg1_kernel<<<(NB * NN + 3) / 4, 256, 0, stream>>>(h1b, es1, ed1, b1, W2, a2s, a2d,
                                                       rowptr, col, h2, es2, ed2);
    agg2_kernel<<<(NB * NN + 255) / 256, 256, 0, stream>>>(h2, es2, ed2, b2, rowptr, col, out);
}